// Round 4
// baseline (214.479 us; speedup 1.0000x reference)
//
#include <hip/hip_runtime.h>
#include <hip/hip_bf16.h>
#include <math.h>

#define C_CLASSES 100000
#define EMBED     384
#define BATCH     512
#define S_SCALE   64.0f
#define COS_M_    0.8775825618903728f
#define SIN_M_    0.479425538604203f
#define TH_       (-0.8775825618903728f)
#define MM_       0.2397127693021015f
#define EPS_      1e-7f
#define LOG2E_    1.4426950408889634f
#define LN2_      0.6931471805599453f

#define CT    64
#define NCH   1563                 // ceil(100000/64)
#define NBLK  256                  // persistent blocks; chunk = blk + NBLK*k

typedef __attribute__((ext_vector_type(8))) short bf16x8;
typedef __attribute__((ext_vector_type(4))) float f32x4;

__device__ inline ushort f2bf(float f) {
    unsigned u = __float_as_uint(f);
    unsigned r = (u + 0x7fffu + ((u >> 16) & 1u)) >> 16;   // RNE
    return (ushort)r;
}

// ---------------------------------------------------------------------------
// Kernel 0: convert E to bf16, packed in MFMA A-fragment order:
//   eP[((tile*12 + ks)*64 + lane)*8 + j] = bf16(E[tile*16 + (lane&15)]
//                                               [ks*32 + (lane>>4)*8 + j])
// ---------------------------------------------------------------------------
__global__ __launch_bounds__(256)
void cvt_pack_e(const float* __restrict__ emb, ushort* __restrict__ eP)
{
    int t = blockIdx.x * 256 + threadIdx.x;      // 0 .. 24575
    int lane = t & 63;
    int grp  = t >> 6;                           // tile*12 + ks
    int tile = grp / 12, ks = grp % 12;
    int lr = lane & 15, lg = lane >> 4;
    int row = tile * 16 + lr;
    int col = ks * 32 + lg * 8;
    const float4* src = (const float4*)(emb + (size_t)row * EMBED + col);
    float4 v0 = src[0], v1 = src[1];
    ushort4 o0, o1;
    o0.x = f2bf(v0.x); o0.y = f2bf(v0.y); o0.z = f2bf(v0.z); o0.w = f2bf(v0.w);
    o1.x = f2bf(v1.x); o1.y = f2bf(v1.y); o1.z = f2bf(v1.z); o1.w = f2bf(v1.w);
    ((ushort4*)eP)[t * 2]     = o0;
    ((ushort4*)eP)[t * 2 + 1] = o1;
}

// ---------------------------------------------------------------------------
// Kernel A: persistent blocks, chunk loop with register prefetch +
// double-buffered swizzled LDS + online per-lane LSE accumulation.
// grid = 256 x 1024 threads (16 waves, 1 block/CU).
// ---------------------------------------------------------------------------
__global__ __launch_bounds__(1024, 4)
void arc_main(const ushort* __restrict__ eP, const int* __restrict__ labels,
              const float* __restrict__ weight,
              float* __restrict__ pmax, float* __restrict__ psum,
              float* __restrict__ zlabel)
{
    __shared__ ushort Wl[2][CT * EMBED];     // 2 x 49152 B

    const int tid = threadIdx.x;
    const int blk = blockIdx.x;
    const int nch = NCH / NBLK + ((blk < (NCH % NBLK)) ? 1 : 0);   // 6 or 7

    const int c  = tid >> 4;      // class within chunk (0..63)
    const int p  = tid & 15;      // quad group within row
    const int wid = tid >> 6;     // wave 0..15
    const int l  = tid & 63;
    const int lr = l & 15;
    const int lg = l >> 4;

    // labels for the 8 rows this thread's accumulators own (fixed all chunks)
    int labr[2][4];
    #pragma unroll
    for (int mt = 0; mt < 2; ++mt)
        #pragma unroll
        for (int rg = 0; rg < 4; ++rg)
            labr[mt][rg] = labels[wid * 32 + mt * 16 + lg * 4 + rg];

    // per-lane running logsumexp state (log2 domain), per owned row
    float m_l[2][4], s_l[2][4];
    #pragma unroll
    for (int mt = 0; mt < 2; ++mt)
        #pragma unroll
        for (int rg = 0; rg < 4; ++rg) { m_l[mt][rg] = -1e30f; s_l[mt][rg] = 0.f; }

    const ushort* abase = eP + ((size_t)(wid * 2) * 12 * 64 + l) * 8;

    // ---- prefetch chunk 0 into registers ----
    int ch = blk;
    int row = ch * CT + c;
    bool valid = row < C_CLASSES;
    const float4* wp = (const float4*)(weight +
                        (size_t)(valid ? row : (C_CLASSES - 1)) * EMBED) + p;
    float4 wv[6];
    #pragma unroll
    for (int i = 0; i < 6; ++i) wv[i] = wp[16 * i];

    for (int k = 0; k < nch; ++k) {
        const int cur = k & 1;
        const int c0  = ch * CT;

        // ---- normalize from registers (16 lanes per class) ----
        float ss = 0.f;
        #pragma unroll
        for (int i = 0; i < 6; ++i)
            ss += wv[i].x * wv[i].x + wv[i].y * wv[i].y
                + wv[i].z * wv[i].z + wv[i].w * wv[i].w;
        #pragma unroll
        for (int d = 1; d < 16; d <<= 1) ss += __shfl_xor(ss, d, 64);
        const float inv = (valid && ss > 0.f) ? rsqrtf(ss) : 0.f;

        // ---- cvt bf16 + swizzled store into LDS[cur] ----
        #pragma unroll
        for (int i = 0; i < 6; ++i) {
            int q   = p + 16 * i;
            int idx = c * EMBED + q * 4;
            int sw  = idx ^ ((c & 7) << 3);
            ushort4 o;
            o.x = f2bf(wv[i].x * inv); o.y = f2bf(wv[i].y * inv);
            o.z = f2bf(wv[i].z * inv); o.w = f2bf(wv[i].w * inv);
            *(ushort4*)&Wl[cur][sw] = o;
        }

        // ---- issue prefetch of next chunk (stays in flight across barrier) --
        int ch2   = (k + 1 < nch) ? ch + NBLK : blk;
        int row2  = ch2 * CT + c;
        bool valid2 = row2 < C_CLASSES;
        const float4* wp2 = (const float4*)(weight +
                             (size_t)(valid2 ? row2 : (C_CLASSES - 1)) * EMBED) + p;
        #pragma unroll
        for (int i = 0; i < 6; ++i) wv[i] = wp2[16 * i];

        // barrier WITHOUT vmcnt drain: only LDS stores must be visible
        asm volatile("s_waitcnt lgkmcnt(0)" ::: "memory");
        __builtin_amdgcn_s_barrier();

        // ---- MFMA: wave covers 2 M-tiles x 4 N-tiles, K=384 ----
        f32x4 acc[2][4];
        #pragma unroll
        for (int mt = 0; mt < 2; ++mt)
            #pragma unroll
            for (int nt = 0; nt < 4; ++nt)
                acc[mt][nt] = (f32x4){0.f, 0.f, 0.f, 0.f};

        #pragma unroll
        for (int ks = 0; ks < 12; ++ks) {
            bf16x8 a0 = *(const bf16x8*)(abase + ks * 512);
            bf16x8 a1 = *(const bf16x8*)(abase + (12 + ks) * 512);
            bf16x8 b[4];
            #pragma unroll
            for (int nt = 0; nt < 4; ++nt) {
                int cc  = nt * 16 + lr;
                int idx = cc * EMBED + ks * 32 + lg * 8;
                b[nt] = *(const bf16x8*)&Wl[cur][idx ^ ((cc & 7) << 3)];
            }
            #pragma unroll
            for (int nt = 0; nt < 4; ++nt) {
                acc[0][nt] = __builtin_amdgcn_mfma_f32_16x16x32_bf16(
                    a0, b[nt], acc[0][nt], 0, 0, 0);
                acc[1][nt] = __builtin_amdgcn_mfma_f32_16x16x32_bf16(
                    a1, b[nt], acc[1][nt], 0, 0, 0);
            }
        }

        // ---- epilogue: margin + per-lane online LSE (no shuffles) ----
        #pragma unroll
        for (int mt = 0; mt < 2; ++mt) {
            #pragma unroll
            for (int rg = 0; rg < 4; ++rg) {
                const int lab = labr[mt][rg];
                float z[4];
                #pragma unroll
                for (int nt = 0; nt < 4; ++nt) {
                    int gc = c0 + nt * 16 + lr;
                    float cosv = acc[mt][nt][rg];
                    cosv = fminf(fmaxf(cosv, -1.f + EPS_), 1.f - EPS_);
                    float zz = S_SCALE * cosv;
                    if (gc == lab) {
                        float zm;
                        if (cosv > TH_) {
                            float sv = sqrtf(fmaxf(1.f - cosv * cosv, 0.f));
                            zm = S_SCALE * (cosv * COS_M_ - sv * SIN_M_);
                        } else {
                            zm = S_SCALE * (cosv - MM_);
                        }
                        zlabel[wid * 32 + mt * 16 + lg * 4 + rg] = zm;
                        zz = zm;
                    }
                    z[nt] = (gc >= C_CLASSES) ? -1e30f : zz * LOG2E_;
                }
                float m4 = fmaxf(fmaxf(z[0], z[1]), fmaxf(z[2], z[3]));
                float M  = fmaxf(m_l[mt][rg], m4);
                float sn = exp2f(z[0] - M) + exp2f(z[1] - M)
                         + exp2f(z[2] - M) + exp2f(z[3] - M);
                s_l[mt][rg] = s_l[mt][rg] * exp2f(m_l[mt][rg] - M) + sn;
                m_l[mt][rg] = M;
            }
        }

        ch = ch2; valid = valid2;
    }

    // ---- final 16-lane merge per owned row, write one partial per block ----
    #pragma unroll
    for (int mt = 0; mt < 2; ++mt) {
        #pragma unroll
        for (int rg = 0; rg < 4; ++rg) {
            float m = m_l[mt][rg], s = s_l[mt][rg];
            #pragma unroll
            for (int d = 1; d < 16; d <<= 1) {
                float m2 = __shfl_xor(m, d, 64);
                float s2 = __shfl_xor(s, d, 64);
                float M  = fmaxf(m, m2);
                s = s * exp2f(m - M) + s2 * exp2f(m2 - M);
                m = M;
            }
            if (lr == 0) {
                int r = wid * 32 + mt * 16 + lg * 4 + rg;
                pmax[(size_t)blk * BATCH + r] = m;
                psum[(size_t)blk * BATCH + r] = s;
            }
        }
    }
}

// ---------------------------------------------------------------------------
// Kernel B: merge 256 block-partials per row (log2 domain) -> row loss
// ---------------------------------------------------------------------------
__global__ __launch_bounds__(256)
void arc_reduce(const float* __restrict__ pmax, const float* __restrict__ psum,
                const float* __restrict__ zlabel, float* __restrict__ rowloss)
{
    const int r = blockIdx.x;
    const int tid = threadIdx.x;
    float m = pmax[(size_t)tid * BATCH + r];
    float s = psum[(size_t)tid * BATCH + r];
    #pragma unroll
    for (int d = 1; d < 64; d <<= 1) {
        float m2 = __shfl_xor(m, d, 64);
        float s2 = __shfl_xor(s, d, 64);
        float M = fmaxf(m, m2);
        s = s * exp2f(m - M) + s2 * exp2f(m2 - M);
        m = M;
    }
    __shared__ float sm[4], ssh[4];
    if ((tid & 63) == 0) { sm[tid >> 6] = m; ssh[tid >> 6] = s; }
    __syncthreads();
    if (tid == 0) {
        m = sm[0]; s = ssh[0];
        #pragma unroll
        for (int w = 1; w < 4; ++w) {
            float M = fmaxf(m, sm[w]);
            s = s * exp2f(m - M) + ssh[w] * exp2f(sm[w] - M);
            m = M;
        }
        rowloss[r] = LN2_ * (m + log2f(s)) - zlabel[r];
    }
}

// ---------------------------------------------------------------------------
// Kernel C: mean over rows
// ---------------------------------------------------------------------------
__global__ __launch_bounds__(512)
void arc_mean(const float* __restrict__ rowloss, float* __restrict__ out)
{
    const int tid = threadIdx.x;
    float v = rowloss[tid];
    #pragma unroll
    for (int d = 1; d < 64; d <<= 1) v += __shfl_xor(v, d, 64);
    __shared__ float sv[8];
    if ((tid & 63) == 0) sv[tid >> 6] = v;
    __syncthreads();
    if (tid == 0) {
        float t = 0.f;
        #pragma unroll
        for (int w = 0; w < 8; ++w) t += sv[w];
        out[0] = t / (float)BATCH;
    }
}

extern "C" void kernel_launch(void* const* d_in, const int* in_sizes, int n_in,
                              void* d_out, int out_size, void* d_ws, size_t ws_size,
                              hipStream_t stream)
{
    (void)in_sizes; (void)n_in; (void)out_size; (void)ws_size;
    const float* emb    = (const float*)d_in[0];
    const int*   labels = (const int*)d_in[1];
    const float* weight = (const float*)d_in[2];
    float* out = (float*)d_out;

    float* pmax    = (float*)d_ws;                    // [NBLK][BATCH]
    float* psum    = pmax + (size_t)NBLK * BATCH;     // [NBLK][BATCH]
    float* zlabel  = psum + (size_t)NBLK * BATCH;     // [BATCH]
    float* rowloss = zlabel + BATCH;                  // [BATCH]
    ushort* eP     = (ushort*)(rowloss + BATCH);      // packed bf16 E fragments

    cvt_pack_e<<<(BATCH * EMBED / 8) / 256, 256, 0, stream>>>(emb, eP);
    arc_main<<<NBLK, 1024, 0, stream>>>(eP, labels, weight, pmax, psum, zlabel);
    arc_reduce<<<BATCH, 256, 0, stream>>>(pmax, psum, zlabel, rowloss);
    arc_mean<<<1, 512, 0, stream>>>(rowloss, out);
}